// Round 11
// baseline (202.391 us; speedup 1.0000x reference)
//
#include <hip/hip_runtime.h>

// FGKAN scoring kernel for MI355X (gfx950).
//
// Restructure: x@W1 = h_set@W1_top + path@W1_bot.
//   - h_set is a SUM of entity rows  -> precompute tab = [entB|PentB] bf16
//   - path is a PRODUCT of relation rows -> relB bf16 (rows 0..31 = Prel1,
//     rows 32..1055 = Prel2[r0*32+r1]).
//
// R10 post-mortem: bf16 table: k_main 91.5->66us, FETCH 311->147MB (~= full
// logical gather volume: random gathers miss per-XCD L2, stream from L3 at
// 2.3TB/s). VGPR 52 => compiler kept ~2 iters of gathers in flight; 66us is
// latency/MLP-bound (pure VALU demand ~20us). proj ~46us, residual ~85us.
// R11: (1) k_main: hoist all indices to regs, batch ALL phase-A gathers
// (40 loads in flight), issue phase-C gathers under phase-B shuffles;
// (2) rel tables bf16 (halves those bytes); (3) k_proj_ent: read W1 from
// L1 instead of LDS (halves LDS -> 8 blocks/CU, fewer barriers).
//
// d_ws layout: relB (1056*64 bf16 = 132KB) | tab (NE x 128 bf16 = 25.6MB)

#define NE   100000
#define NR   32
#define DIMD 64
#define BB   4096
#define TT   32
#define BT   (BB * TT)

__device__ __forceinline__ float sigf(float x) { return 1.0f / (1.0f + __expf(-x)); }
__device__ __forceinline__ float4 ld4(const float* p) {
    return *reinterpret_cast<const float4*>(p);
}

// bf16 helpers (manual RNE pack / shift unpack)
__device__ __forceinline__ float b2f(unsigned short u) {
    return __builtin_bit_cast(float, ((unsigned)u) << 16);
}
__device__ __forceinline__ unsigned short f2b(float x) {
    unsigned b = __builtin_bit_cast(unsigned, x);
    b += 0x7FFF + ((b >> 16) & 1);
    return (unsigned short)(b >> 16);
}
__device__ __forceinline__ float4 u2f4(ushort4 v) {
    return make_float4(b2f(v.x), b2f(v.y), b2f(v.z), b2f(v.w));
}
__device__ __forceinline__ ushort4 ldu4(const unsigned short* p) {
    return *reinterpret_cast<const ushort4*>(p);
}

// v_add_f32 with DPP row_ror:N source (16-lane row rotate) — VALU-speed reduce.
template <int CTRL>
__device__ __forceinline__ float dpp_add(float x) {
    int r = __builtin_amdgcn_update_dpp(0, __builtin_bit_cast(int, x), CTRL,
                                        0xf, 0xf, true);
    return x + __builtin_bit_cast(float, r);
}
__device__ __forceinline__ float reduce16(float x) {
    x = dpp_add<0x121>(x);  // row_ror:1
    x = dpp_add<0x122>(x);  // row_ror:2
    x = dpp_add<0x124>(x);  // row_ror:4
    x = dpp_add<0x128>(x);  // row_ror:8
    return x;
}

// ---------------------------------------------------------------- precompute
// tab row r (256B) = [ entB: 64 bf16 | PentB: 64 bf16 ], Pent = ent @ W1_top.
// 64 rows/block; rows staged in LDS, W1 read direct (L1-resident 16KB).
__global__ __launch_bounds__(256) void k_proj_ent(const float* __restrict__ ent,
                                                  const float* __restrict__ W1,
                                                  unsigned short* __restrict__ tab) {
    __shared__ float sR[64][68];
    const int tid = threadIdx.x;
    const int row0 = blockIdx.x * 64;

#pragma unroll
    for (int i = 0; i < 4; ++i) {
        const int idx = tid + 256 * i;        // 0..1023
        const int r = idx >> 4;
        const int c = idx & 15;
        const int er = (row0 + r < NE) ? (row0 + r) : (NE - 1);
        const float4 rv = ld4(ent + er * DIMD + 4 * c);
        sR[r][4 * c + 0] = rv.x; sR[r][4 * c + 1] = rv.y;
        sR[r][4 * c + 2] = rv.z; sR[r][4 * c + 3] = rv.w;
    }
    __syncthreads();

    const int q = tid & 15;
    const int trow = tid >> 4;
    float4 acc0 = make_float4(0.f, 0.f, 0.f, 0.f);
    float4 acc1 = acc0, acc2 = acc0, acc3 = acc0;

#pragma unroll
    for (int kk = 0; kk < 16; ++kk) {
        const float4 r0 = ld4(&sR[4 * trow + 0][4 * kk]);
        const float4 r1 = ld4(&sR[4 * trow + 1][4 * kk]);
        const float4 r2 = ld4(&sR[4 * trow + 2][4 * kk]);
        const float4 r3 = ld4(&sR[4 * trow + 3][4 * kk]);
#pragma unroll
        for (int i = 0; i < 4; ++i) {
            const float4 wv = ld4(W1 + (4 * kk + i) * DIMD + 4 * q);
            const float s0 = (i == 0) ? r0.x : (i == 1) ? r0.y : (i == 2) ? r0.z : r0.w;
            const float s1 = (i == 0) ? r1.x : (i == 1) ? r1.y : (i == 2) ? r1.z : r1.w;
            const float s2 = (i == 0) ? r2.x : (i == 1) ? r2.y : (i == 2) ? r2.z : r2.w;
            const float s3 = (i == 0) ? r3.x : (i == 1) ? r3.y : (i == 2) ? r3.z : r3.w;
            acc0.x = fmaf(s0, wv.x, acc0.x); acc0.y = fmaf(s0, wv.y, acc0.y);
            acc0.z = fmaf(s0, wv.z, acc0.z); acc0.w = fmaf(s0, wv.w, acc0.w);
            acc1.x = fmaf(s1, wv.x, acc1.x); acc1.y = fmaf(s1, wv.y, acc1.y);
            acc1.z = fmaf(s1, wv.z, acc1.z); acc1.w = fmaf(s1, wv.w, acc1.w);
            acc2.x = fmaf(s2, wv.x, acc2.x); acc2.y = fmaf(s2, wv.y, acc2.y);
            acc2.z = fmaf(s2, wv.z, acc2.z); acc2.w = fmaf(s2, wv.w, acc2.w);
            acc3.x = fmaf(s3, wv.x, acc3.x); acc3.y = fmaf(s3, wv.y, acc3.y);
            acc3.z = fmaf(s3, wv.z, acc3.z); acc3.w = fmaf(s3, wv.w, acc3.w);
        }
    }

    const int orow = row0 + 4 * trow;
#pragma unroll
    for (int i = 0; i < 4; ++i) {
        if (orow + i < NE) {
            const float4 a = (i == 0) ? acc0 : (i == 1) ? acc1 : (i == 2) ? acc2 : acc3;
            unsigned short* rowp = tab + ((size_t)(orow + i) << 7);
            ushort4 ev, pv;
            ev.x = f2b(sR[4 * trow + i][4 * q + 0]);
            ev.y = f2b(sR[4 * trow + i][4 * q + 1]);
            ev.z = f2b(sR[4 * trow + i][4 * q + 2]);
            ev.w = f2b(sR[4 * trow + i][4 * q + 3]);
            pv.x = f2b(a.x); pv.y = f2b(a.y); pv.z = f2b(a.z); pv.w = f2b(a.w);
            *reinterpret_cast<ushort4*>(rowp + 4 * q) = ev;
            *reinterpret_cast<ushort4*>(rowp + 64 + 4 * q) = pv;
        }
    }
}

// relB rows: [0,32) = rel[r] @ W1_bot ; [32,1056+32... ) wait: rows 32..1055+32
// relB[32 + r0*32 + r1] = (rel[r0]*rel[r1]) @ W1_bot. 1056 rows total... 1088.
__global__ __launch_bounds__(256) void k_proj_rel(const float* __restrict__ rel,
                                                  const float* __restrict__ W1,
                                                  unsigned short* __restrict__ relB) {
    int gid = blockIdx.x * 256 + threadIdx.x;
    int row = gid >> 6;
    int d = gid & 63;
    if (row < 32) {
        const float* a = rel + row * DIMD;
        float acc = 0.0f;
#pragma unroll
        for (int k = 0; k < DIMD; ++k)
            acc = fmaf(a[k], W1[(DIMD + k) * DIMD + d], acc);
        relB[row * DIMD + d] = f2b(acc);
    } else if (row < 32 + 1024) {
        const int rr = row - 32;
        const float* a = rel + (rr >> 5) * DIMD;
        const float* c = rel + (rr & 31) * DIMD;
        float acc = 0.0f;
#pragma unroll
        for (int k = 0; k < DIMD; ++k)
            acc = fmaf(a[k] * c[k], W1[(DIMD + k) * DIMD + d], acc);
        relB[row * DIMD + d] = f2b(acc);
    }
}

// ---------------------------------------------------------------- main
// One block per b. Wave w = branch. Lane = (g in [0,4), q in [0,16)).
// All indices hoisted to regs; phase-A gathers batched (40 in flight);
// phase-C gathers issued before phase-B reduces.
__global__ __launch_bounds__(256) void k_main(
    const int* __restrict__ items,
    const int* __restrict__ uh, const int* __restrict__ ur, const int* __restrict__ ut,
    const int* __restrict__ ih, const int* __restrict__ ir, const int* __restrict__ itp,
    const int* __restrict__ ph, const int* __restrict__ pr, const int* __restrict__ pt,
    const int* __restrict__ oh, const int* __restrict__ orr, const int* __restrict__ ot,
    const unsigned short* __restrict__ tab,
    const unsigned short* __restrict__ relB,
    const float* __restrict__ W2,
    float* __restrict__ out) {
    const int b = blockIdx.x;
    const int tid = threadIdx.x;
    const int w = tid >> 6;
    const int lane = tid & 63;
    const int g = lane >> 4;
    const int q = lane & 15;

    const int* hp;
    const int* rp;
    const int* tp;
    switch (w) {
        case 0: hp = uh; rp = ur; tp = ut; break;
        case 1: hp = ih; rp = ir; tp = itp; break;
        case 2: hp = ph; rp = pr; tp = pt; break;
        default: hp = oh; rp = orr; tp = ot; break;
    }

    // stage this block's indices in LDS (coalesced), then hoist to registers
    __shared__ int sidx[4][3][2][TT];
    {
        const int l = lane >> 5;
        const int t0 = lane & 31;
        const int off = l * BT + b * TT + t0;
        sidx[w][0][l][t0] = hp[off];
        sidx[w][1][l][t0] = rp[off];
        sidx[w][2][l][t0] = tp[off];
    }
    const int item_idx = (w == 1) ? items[b] : 0;

    int jh0[8], jh1[8], jr0[8], jr1[8], jt0[8], jt1[8];
#pragma unroll
    for (int p = 0; p < 8; ++p) {
        const int t = 4 * p + g;
        jh0[p] = sidx[w][0][0][t];
        jh1[p] = sidx[w][0][1][t];
        jr0[p] = sidx[w][1][0][t];
        jr1[p] = sidx[w][1][1][t];
        jt0[p] = sidx[w][2][0][t];
        jt1[p] = sidx[w][2][1][t];
    }

    // ---- batched Phase-A gathers: 40 loads issued before any compute
    ushort4 rH[8], rA0[8], rA1[8], rR0[8], rR2[8];
#pragma unroll
    for (int p = 0; p < 8; ++p) {
        const unsigned short* r0p = tab + ((size_t)jh0[p] << 7) + 4 * q;
        rH[p] = ldu4(r0p);
        rA0[p] = ldu4(r0p + 64);
        rA1[p] = ldu4(tab + ((size_t)jh1[p] << 7) + 64 + 4 * q);
        rR0[p] = ldu4(relB + ((size_t)jr0[p] << 6) + 4 * q);
        rR2[p] = ldu4(relB + ((size_t)(32 + jr0[p] * 32 + jr1[p]) << 6) + 4 * q);
    }

    const float4 w2v = ld4(W2 + 4 * q);

    // ---- Phase A compute (pure register math)
    float d0[8], d1[8];
    float4 accH = make_float4(0.f, 0.f, 0.f, 0.f);
#pragma unroll
    for (int p = 0; p < 8; ++p) {
        const float4 H = u2f4(rH[p]);
        const float4 A0 = u2f4(rA0[p]);
        const float4 A1 = u2f4(rA1[p]);
        const float4 R0 = u2f4(rR0[p]);
        const float4 R2 = u2f4(rR2[p]);

        accH.x += H.x; accH.y += H.y; accH.z += H.z; accH.w += H.w;

        float v = sigf(A0.x + R0.x) * w2v.x;
        v = fmaf(sigf(A0.y + R0.y), w2v.y, v);
        v = fmaf(sigf(A0.z + R0.z), w2v.z, v);
        v = fmaf(sigf(A0.w + R0.w), w2v.w, v);
        d0[p] = v;

        float u = sigf(A0.x + A1.x + R2.x) * w2v.x;
        u = fmaf(sigf(A0.y + A1.y + R2.y), w2v.y, u);
        u = fmaf(sigf(A0.z + A1.z + R2.z), w2v.z, u);
        u = fmaf(sigf(A0.w + A1.w + R2.w), w2v.w, u);
        d1[p] = u;
    }

    // ---- issue Phase-C gathers now; their latency hides under Phase B
    ushort4 rT0[8], rT1[8];
#pragma unroll
    for (int p = 0; p < 8; ++p) {
        rT0[p] = ldu4(tab + ((size_t)jt0[p] << 7) + 4 * q);
        rT1[p] = ldu4(tab + ((size_t)jt1[p] << 7) + 4 * q);
    }
    const ushort4 rIt = ldu4(tab + ((size_t)item_idx << 7) + 4 * q);

    // ---- Phase B: batched 16-lane DPP reduces; e = exp(sigmoid(dot)).
    float e0[8], e1[8];
    float s0 = 0.0f, s1 = 0.0f;
#pragma unroll
    for (int p = 0; p < 8; ++p) {
        e0[p] = __expf(sigf(reduce16(d0[p])));
        e1[p] = __expf(sigf(reduce16(d1[p])));
        s0 += e0[p];
        s1 += e1[p];
    }
    s0 += __shfl_xor(s0, 16, 64);
    s0 += __shfl_xor(s0, 32, 64);
    s1 += __shfl_xor(s1, 16, 64);
    s1 += __shfl_xor(s1, 32, 64);

    // ---- Phase C: unnormalized weighted t-emb sums (entB halves)
    float4 acc0 = make_float4(0.f, 0.f, 0.f, 0.f);
    float4 acc1 = acc0;
#pragma unroll
    for (int p = 0; p < 8; ++p) {
        const float4 T0 = u2f4(rT0[p]);
        const float4 T1 = u2f4(rT1[p]);
        acc0.x = fmaf(e0[p], T0.x, acc0.x); acc0.y = fmaf(e0[p], T0.y, acc0.y);
        acc0.z = fmaf(e0[p], T0.z, acc0.z); acc0.w = fmaf(e0[p], T0.w, acc0.w);
        acc1.x = fmaf(e1[p], T1.x, acc1.x); acc1.y = fmaf(e1[p], T1.y, acc1.y);
        acc1.z = fmaf(e1[p], T1.z, acc1.z); acc1.w = fmaf(e1[p], T1.w, acc1.w);
    }

    const float inv0 = 1.0f / s0;
    const float inv1 = 1.0f / s1;
    float4 v;
    v.x = fmaf(acc0.x, inv0, fmaf(acc1.x, inv1, 0.03125f * accH.x));
    v.y = fmaf(acc0.y, inv0, fmaf(acc1.y, inv1, 0.03125f * accH.y));
    v.z = fmaf(acc0.z, inv0, fmaf(acc1.z, inv1, 0.03125f * accH.z));
    v.w = fmaf(acc0.w, inv0, fmaf(acc1.w, inv1, 0.03125f * accH.w));

    // reduce across the 4 t-subgroups
    v.x += __shfl_xor(v.x, 16, 64); v.x += __shfl_xor(v.x, 32, 64);
    v.y += __shfl_xor(v.y, 16, 64); v.y += __shfl_xor(v.y, 32, 64);
    v.z += __shfl_xor(v.z, 16, 64); v.z += __shfl_xor(v.z, 32, 64);
    v.w += __shfl_xor(v.w, 16, 64); v.w += __shfl_xor(v.w, 32, 64);

    if (w == 1) {  // item branch additionally adds ent[items[b]] (entB half)
        const float4 iv = u2f4(rIt);
        v.x += iv.x; v.y += iv.y; v.z += iv.z; v.w += iv.w;
    }

    __shared__ float vec[4][DIMD];
    if (g == 0) {
        vec[w][4 * q + 0] = v.x;
        vec[w][4 * q + 1] = v.y;
        vec[w][4 * q + 2] = v.z;
        vec[w][4 * q + 3] = v.w;
    }
    __syncthreads();

    // score = sigmoid( sum_d e_u*e_p_i + e_p_u*e_i )
    if (tid < 64) {
        float z = fmaf(vec[0][tid], vec[3][tid], vec[2][tid] * vec[1][tid]);
#pragma unroll
        for (int m = 1; m < 64; m <<= 1) z += __shfl_xor(z, m, 64);
        if (tid == 0) out[b] = sigf(z);
    }
    if (b == 0 && tid == 0) out[BB] = 0.0f;  // kge_loss
}

extern "C" void kernel_launch(void* const* d_in, const int* in_sizes, int n_in,
                              void* d_out, int out_size, void* d_ws, size_t ws_size,
                              hipStream_t stream) {
    const int* items = (const int*)d_in[0];
    const int* uh = (const int*)d_in[1];
    const int* ur = (const int*)d_in[2];
    const int* ut = (const int*)d_in[3];
    const int* ih = (const int*)d_in[4];
    const int* ir = (const int*)d_in[5];
    const int* itp = (const int*)d_in[6];
    const int* ph = (const int*)d_in[7];
    const int* pr = (const int*)d_in[8];
    const int* pt = (const int*)d_in[9];
    const int* oh = (const int*)d_in[10];
    const int* orr = (const int*)d_in[11];
    const int* ot = (const int*)d_in[12];
    const float* ent = (const float*)d_in[13];
    const float* rel = (const float*)d_in[14];
    const float* W1 = (const float*)d_in[15];
    const float* W2 = (const float*)d_in[16];
    float* out = (float*)d_out;

    unsigned short* relB = (unsigned short*)d_ws;    // 1056 rows x 64 bf16 = 132KB
    unsigned short* tab = relB + 1056 * DIMD;        // NE x 128 bf16 = 25.6MB

    hipLaunchKernelGGL(k_proj_ent, dim3((NE + 63) / 64), dim3(256), 0, stream,
                       ent, W1, tab);
    hipLaunchKernelGGL(k_proj_rel, dim3((1056 * 64 + 255) / 256), dim3(256), 0,
                       stream, rel, W1, relB);
    hipLaunchKernelGGL(k_main, dim3(BB), dim3(256), 0, stream, items, uh, ur, ut,
                       ih, ir, itp, ph, pr, pt, oh, orr, ot, tab, relB, W2, out);
}

// Round 12
// 194.040 us; speedup vs baseline: 1.0430x; 1.0430x over previous
//
#include <hip/hip_runtime.h>

// FGKAN scoring kernel for MI355X (gfx950).
//
// Restructure: x@W1 = h_set@W1_top + path@W1_bot.
//   tab = [entB|PentB] bf16 256B rows; relB bf16 (row 0..31 = Prel1,
//   rows 32..1055+32 = Prel2[r0*32+r1]).
//
// R11 post-mortem: load batching = null (65us, FETCH unchanged) while
// VALUBusy ~90% -> VALU-issue is the tracking resource. Both kernels run
// ~4-5x above 2.4GHz issue models (effective clock / model gap) -> cut
// instruction count, not latency tricks.
// R12: (1) k_main remapped to 8 dims/lane x 8 t-groups (p-loop 8->4):
// halves addr math, Phase-B transcendental redundancy, shuffle steps;
// gathers become dwordx4 (28 loads vs 56). (2) k_proj_ent reverted to
// proven R10 LDS-tiled form.
//
// d_ws layout: relB (1056*64 bf16 = 132KB) | tab (NE x 128 bf16 = 25.6MB)

#define NE   100000
#define NR   32
#define DIMD 64
#define BB   4096
#define TT   32
#define BT   (BB * TT)

__device__ __forceinline__ float sigf(float x) { return 1.0f / (1.0f + __expf(-x)); }
__device__ __forceinline__ float4 ld4(const float* p) {
    return *reinterpret_cast<const float4*>(p);
}

// bf16 helpers
__device__ __forceinline__ unsigned short f2b(float x) {
    unsigned b = __builtin_bit_cast(unsigned, x);
    b += 0x7FFF + ((b >> 16) & 1);
    return (unsigned short)(b >> 16);
}
__device__ __forceinline__ float blo(unsigned u) {
    return __builtin_bit_cast(float, u << 16);
}
__device__ __forceinline__ float bhi(unsigned u) {
    return __builtin_bit_cast(float, u & 0xFFFF0000u);
}
// unpack 8 bf16 (uint4) -> 8 f32
__device__ __forceinline__ void unp8(uint4 v, float* f) {
    f[0] = blo(v.x); f[1] = bhi(v.x);
    f[2] = blo(v.y); f[3] = bhi(v.y);
    f[4] = blo(v.z); f[5] = bhi(v.z);
    f[6] = blo(v.w); f[7] = bhi(v.w);
}
__device__ __forceinline__ uint4 ldu4(const unsigned* p) {
    return *reinterpret_cast<const uint4*>(p);
}

// sum across 8-lane group (lanes differing in bits 0..2)
__device__ __forceinline__ float reduce8(float x) {
    x += __shfl_xor(x, 1, 64);
    x += __shfl_xor(x, 2, 64);
    x += __shfl_xor(x, 4, 64);
    return x;
}

// ---------------------------------------------------------------- precompute
// tab row r (256B) = [ entB: 64 bf16 | PentB: 64 bf16 ], Pent = ent @ W1_top.
// R10-proven LDS-tiled GEMM: 64 rows/block, 256 threads.
__global__ __launch_bounds__(256) void k_proj_ent(const float* __restrict__ ent,
                                                  const float* __restrict__ W1,
                                                  unsigned short* __restrict__ tab) {
    __shared__ float sW[64][68];
    __shared__ float sR[64][68];
    const int tid = threadIdx.x;
    const int row0 = blockIdx.x * 64;

#pragma unroll
    for (int i = 0; i < 4; ++i) {
        const int idx = tid + 256 * i;        // 0..1023
        const int r = idx >> 4;
        const int c = idx & 15;
        const float4 wv = ld4(W1 + r * DIMD + 4 * c);
        sW[r][4 * c + 0] = wv.x; sW[r][4 * c + 1] = wv.y;
        sW[r][4 * c + 2] = wv.z; sW[r][4 * c + 3] = wv.w;
        const int er = (row0 + r < NE) ? (row0 + r) : (NE - 1);
        const float4 rv = ld4(ent + er * DIMD + 4 * c);
        sR[r][4 * c + 0] = rv.x; sR[r][4 * c + 1] = rv.y;
        sR[r][4 * c + 2] = rv.z; sR[r][4 * c + 3] = rv.w;
    }
    __syncthreads();

    const int q = tid & 15;
    const int trow = tid >> 4;
    float4 acc0 = make_float4(0.f, 0.f, 0.f, 0.f);
    float4 acc1 = acc0, acc2 = acc0, acc3 = acc0;

#pragma unroll
    for (int kk = 0; kk < 16; ++kk) {
        const float4 r0 = ld4(&sR[4 * trow + 0][4 * kk]);
        const float4 r1 = ld4(&sR[4 * trow + 1][4 * kk]);
        const float4 r2 = ld4(&sR[4 * trow + 2][4 * kk]);
        const float4 r3 = ld4(&sR[4 * trow + 3][4 * kk]);
#pragma unroll
        for (int i = 0; i < 4; ++i) {
            const float4 wv = ld4(&sW[4 * kk + i][4 * q]);
            const float s0 = (i == 0) ? r0.x : (i == 1) ? r0.y : (i == 2) ? r0.z : r0.w;
            const float s1 = (i == 0) ? r1.x : (i == 1) ? r1.y : (i == 2) ? r1.z : r1.w;
            const float s2 = (i == 0) ? r2.x : (i == 1) ? r2.y : (i == 2) ? r2.z : r2.w;
            const float s3 = (i == 0) ? r3.x : (i == 1) ? r3.y : (i == 2) ? r3.z : r3.w;
            acc0.x = fmaf(s0, wv.x, acc0.x); acc0.y = fmaf(s0, wv.y, acc0.y);
            acc0.z = fmaf(s0, wv.z, acc0.z); acc0.w = fmaf(s0, wv.w, acc0.w);
            acc1.x = fmaf(s1, wv.x, acc1.x); acc1.y = fmaf(s1, wv.y, acc1.y);
            acc1.z = fmaf(s1, wv.z, acc1.z); acc1.w = fmaf(s1, wv.w, acc1.w);
            acc2.x = fmaf(s2, wv.x, acc2.x); acc2.y = fmaf(s2, wv.y, acc2.y);
            acc2.z = fmaf(s2, wv.z, acc2.z); acc2.w = fmaf(s2, wv.w, acc2.w);
            acc3.x = fmaf(s3, wv.x, acc3.x); acc3.y = fmaf(s3, wv.y, acc3.y);
            acc3.z = fmaf(s3, wv.z, acc3.z); acc3.w = fmaf(s3, wv.w, acc3.w);
        }
    }

    const int orow = row0 + 4 * trow;
#pragma unroll
    for (int i = 0; i < 4; ++i) {
        if (orow + i < NE) {
            const float4 a = (i == 0) ? acc0 : (i == 1) ? acc1 : (i == 2) ? acc2 : acc3;
            unsigned short* rowp = tab + ((size_t)(orow + i) << 7);
            ushort4 ev, pv;
            ev.x = f2b(sR[4 * trow + i][4 * q + 0]);
            ev.y = f2b(sR[4 * trow + i][4 * q + 1]);
            ev.z = f2b(sR[4 * trow + i][4 * q + 2]);
            ev.w = f2b(sR[4 * trow + i][4 * q + 3]);
            pv.x = f2b(a.x); pv.y = f2b(a.y); pv.z = f2b(a.z); pv.w = f2b(a.w);
            *reinterpret_cast<ushort4*>(rowp + 4 * q) = ev;
            *reinterpret_cast<ushort4*>(rowp + 64 + 4 * q) = pv;
        }
    }
}

// relB rows: [0,32) = rel[r] @ W1_bot ; [32,1056): (rel[r0]*rel[r1]) @ W1_bot
__global__ __launch_bounds__(256) void k_proj_rel(const float* __restrict__ rel,
                                                  const float* __restrict__ W1,
                                                  unsigned short* __restrict__ relB) {
    int gid = blockIdx.x * 256 + threadIdx.x;
    int row = gid >> 6;
    int d = gid & 63;
    if (row < 32) {
        const float* a = rel + row * DIMD;
        float acc = 0.0f;
#pragma unroll
        for (int k = 0; k < DIMD; ++k)
            acc = fmaf(a[k], W1[(DIMD + k) * DIMD + d], acc);
        relB[row * DIMD + d] = f2b(acc);
    } else if (row < 32 + 1024) {
        const int rr = row - 32;
        const float* a = rel + (rr >> 5) * DIMD;
        const float* c = rel + (rr & 31) * DIMD;
        float acc = 0.0f;
#pragma unroll
        for (int k = 0; k < DIMD; ++k)
            acc = fmaf(a[k] * c[k], W1[(DIMD + k) * DIMD + d], acc);
        relB[row * DIMD + d] = f2b(acc);
    }
}

// ---------------------------------------------------------------- main
// One block per b. Wave w = branch. Lane = (g = t-subgroup in [0,8),
// q = 16B dim-chunk in [0,8)). p in [0,4): t = 8p + g. Each lane owns
// dims [8q, 8q+8) of every row -> dwordx4 gathers.
__global__ __launch_bounds__(256) void k_main(
    const int* __restrict__ items,
    const int* __restrict__ uh, const int* __restrict__ ur, const int* __restrict__ ut,
    const int* __restrict__ ih, const int* __restrict__ ir, const int* __restrict__ itp,
    const int* __restrict__ ph, const int* __restrict__ pr, const int* __restrict__ pt,
    const int* __restrict__ oh, const int* __restrict__ orr, const int* __restrict__ ot,
    const unsigned short* __restrict__ tab,
    const unsigned short* __restrict__ relB,
    const float* __restrict__ W2,
    float* __restrict__ out) {
    const int b = blockIdx.x;
    const int tid = threadIdx.x;
    const int w = tid >> 6;
    const int lane = tid & 63;
    const int g = lane >> 3;   // t-subgroup [0,8)
    const int q = lane & 7;    // dim chunk [0,8)

    const int* hp;
    const int* rp;
    const int* tp;
    switch (w) {
        case 0: hp = uh; rp = ur; tp = ut; break;
        case 1: hp = ih; rp = ir; tp = itp; break;
        case 2: hp = ph; rp = pr; tp = pt; break;
        default: hp = oh; rp = orr; tp = ot; break;
    }

    // stage this block's indices in LDS (wave-private; same wave writes/reads)
    __shared__ int sidx[4][3][2][TT];
    {
        const int l = lane >> 5;
        const int t0 = lane & 31;
        const int off = l * BT + b * TT + t0;
        sidx[w][0][l][t0] = hp[off];
        sidx[w][1][l][t0] = rp[off];
        sidx[w][2][l][t0] = tp[off];
    }
    const int item_idx = (w == 1) ? items[b] : 0;

    int jh0[4], jh1[4], jr0[4], jr1[4], jt0[4], jt1[4];
#pragma unroll
    for (int p = 0; p < 4; ++p) {
        const int t = 8 * p + g;
        jh0[p] = sidx[w][0][0][t];
        jh1[p] = sidx[w][0][1][t];
        jr0[p] = sidx[w][1][0][t];
        jr1[p] = sidx[w][1][1][t];
        jt0[p] = sidx[w][2][0][t];
        jt1[p] = sidx[w][2][1][t];
    }

    const unsigned* tabU = (const unsigned*)tab;   // row = 64 uints
    const unsigned* relU = (const unsigned*)relB;  // row = 32 uints

    // ---- batched Phase-A gathers (20 dwordx4 loads)
    uint4 rH[4], rA0[4], rA1[4], rR0[4], rR2[4];
#pragma unroll
    for (int p = 0; p < 4; ++p) {
        const unsigned* r0p = tabU + ((size_t)jh0[p] << 6) + 4 * q;
        rH[p] = ldu4(r0p);
        rA0[p] = ldu4(r0p + 32);
        rA1[p] = ldu4(tabU + ((size_t)jh1[p] << 6) + 32 + 4 * q);
        rR0[p] = ldu4(relU + ((size_t)jr0[p] << 5) + 4 * q);
        rR2[p] = ldu4(relU + ((size_t)(32 + jr0[p] * 32 + jr1[p]) << 5) + 4 * q);
    }

    float w2e[8];
    {
        const float4 wa = ld4(W2 + 8 * q);
        const float4 wb = ld4(W2 + 8 * q + 4);
        w2e[0] = wa.x; w2e[1] = wa.y; w2e[2] = wa.z; w2e[3] = wa.w;
        w2e[4] = wb.x; w2e[5] = wb.y; w2e[6] = wb.z; w2e[7] = wb.w;
    }

    // ---- Phase A compute
    float d0[4], d1[4];
    float aH[8] = {0.f, 0.f, 0.f, 0.f, 0.f, 0.f, 0.f, 0.f};
#pragma unroll
    for (int p = 0; p < 4; ++p) {
        float He[8], A0e[8], A1e[8], R0e[8], R2e[8];
        unp8(rH[p], He);
        unp8(rA0[p], A0e);
        unp8(rA1[p], A1e);
        unp8(rR0[p], R0e);
        unp8(rR2[p], R2e);
        float v = 0.f, u = 0.f;
#pragma unroll
        for (int j = 0; j < 8; ++j) {
            aH[j] += He[j];
            v = fmaf(sigf(A0e[j] + R0e[j]), w2e[j], v);
            u = fmaf(sigf(A0e[j] + A1e[j] + R2e[j]), w2e[j], u);
        }
        d0[p] = v;
        d1[p] = u;
    }

    // ---- issue Phase-C gathers; latency hides under Phase B
    uint4 rT0[4], rT1[4];
#pragma unroll
    for (int p = 0; p < 4; ++p) {
        rT0[p] = ldu4(tabU + ((size_t)jt0[p] << 6) + 4 * q);
        rT1[p] = ldu4(tabU + ((size_t)jt1[p] << 6) + 4 * q);
    }
    const uint4 rIt = ldu4(tabU + ((size_t)item_idx << 6) + 4 * q);

    // ---- Phase B: 8-lane reduces; e = exp(sigmoid(dot)); deferred norm
    float e0[4], e1[4];
    float s0 = 0.f, s1 = 0.f;
#pragma unroll
    for (int p = 0; p < 4; ++p) {
        e0[p] = __expf(sigf(reduce8(d0[p])));
        e1[p] = __expf(sigf(reduce8(d1[p])));
        s0 += e0[p];
        s1 += e1[p];
    }
    s0 += __shfl_xor(s0, 8, 64);
    s0 += __shfl_xor(s0, 16, 64);
    s0 += __shfl_xor(s0, 32, 64);
    s1 += __shfl_xor(s1, 8, 64);
    s1 += __shfl_xor(s1, 16, 64);
    s1 += __shfl_xor(s1, 32, 64);

    // ---- Phase C: unnormalized weighted t-emb sums (entB halves)
    float acc0[8] = {0.f, 0.f, 0.f, 0.f, 0.f, 0.f, 0.f, 0.f};
    float acc1[8] = {0.f, 0.f, 0.f, 0.f, 0.f, 0.f, 0.f, 0.f};
#pragma unroll
    for (int p = 0; p < 4; ++p) {
        float T0e[8], T1e[8];
        unp8(rT0[p], T0e);
        unp8(rT1[p], T1e);
#pragma unroll
        for (int j = 0; j < 8; ++j) {
            acc0[j] = fmaf(e0[p], T0e[j], acc0[j]);
            acc1[j] = fmaf(e1[p], T1e[j], acc1[j]);
        }
    }

    const float inv0 = 1.0f / s0;
    const float inv1 = 1.0f / s1;
    float ve[8];
#pragma unroll
    for (int j = 0; j < 8; ++j) {
        ve[j] = fmaf(acc0[j], inv0, fmaf(acc1[j], inv1, 0.03125f * aH[j]));
        ve[j] += __shfl_xor(ve[j], 8, 64);
        ve[j] += __shfl_xor(ve[j], 16, 64);
        ve[j] += __shfl_xor(ve[j], 32, 64);
    }

    if (w == 1) {  // item branch additionally adds ent[items[b]] (entB half)
        float Ie[8];
        unp8(rIt, Ie);
#pragma unroll
        for (int j = 0; j < 8; ++j) ve[j] += Ie[j];
    }

    __shared__ float vec[4][DIMD];
    if (g == 0) {
#pragma unroll
        for (int j = 0; j < 8; ++j) vec[w][8 * q + j] = ve[j];
    }
    __syncthreads();

    // score = sigmoid( sum_d e_u*e_p_i + e_p_u*e_i )
    if (tid < 64) {
        float z = fmaf(vec[0][tid], vec[3][tid], vec[2][tid] * vec[1][tid]);
#pragma unroll
        for (int m = 1; m < 64; m <<= 1) z += __shfl_xor(z, m, 64);
        if (tid == 0) out[b] = sigf(z);
    }
    if (b == 0 && tid == 0) out[BB] = 0.0f;  // kge_loss
}

extern "C" void kernel_launch(void* const* d_in, const int* in_sizes, int n_in,
                              void* d_out, int out_size, void* d_ws, size_t ws_size,
                              hipStream_t stream) {
    const int* items = (const int*)d_in[0];
    const int* uh = (const int*)d_in[1];
    const int* ur = (const int*)d_in[2];
    const int* ut = (const int*)d_in[3];
    const int* ih = (const int*)d_in[4];
    const int* ir = (const int*)d_in[5];
    const int* itp = (const int*)d_in[6];
    const int* ph = (const int*)d_in[7];
    const int* pr = (const int*)d_in[8];
    const int* pt = (const int*)d_in[9];
    const int* oh = (const int*)d_in[10];
    const int* orr = (const int*)d_in[11];
    const int* ot = (const int*)d_in[12];
    const float* ent = (const float*)d_in[13];
    const float* rel = (const float*)d_in[14];
    const float* W1 = (const float*)d_in[15];
    const float* W2 = (const float*)d_in[16];
    float* out = (float*)d_out;

    unsigned short* relB = (unsigned short*)d_ws;    // 1056 rows x 64 bf16 = 132KB
    unsigned short* tab = relB + 1056 * DIMD;        // NE x 128 bf16 = 25.6MB

    hipLaunchKernelGGL(k_proj_ent, dim3((NE + 63) / 64), dim3(256), 0, stream,
                       ent, W1, tab);
    hipLaunchKernelGGL(k_proj_rel, dim3((1056 * 64 + 255) / 256), dim3(256), 0,
                       stream, rel, W1, relB);
    hipLaunchKernelGGL(k_main, dim3(BB), dim3(256), 0, stream, items, uh, ur, ut,
                       ih, ir, itp, ph, pr, pt, oh, orr, ot, tab, relB, W2, out);
}